// Round 8
// baseline (397.613 us; speedup 1.0000x reference)
//
#include <hip/hip_runtime.h>
#include <hip/hip_bf16.h>

// NSA forward, MI355X round 8. All inputs fp32, output fp32.
// attn_k: role-split (slc|win) grid 1024, 3 blocks/CU, register prefetch of
// next phase's K/V global loads, XCD swizzle (idx&7 ~ (bb,g)), atomicAdd
// epilogue. cmp kept exact-fp32 (top-k must match reference bit-for-bit).
// Shapes: S=4096, seqlen=2048, qh=8, kvh=2, dim=128, blk=64, TOPK=16,
// window=(512,0).

#define SEQ   2048
#define NB    2
#define KV    2
#define NH    4
#define QH    8
#define DIM   128
#define NBLK  32
#define NQB   32
#define NTOP  16
#define SCALE 0.08838834764831845f   // 128^-0.5
#define QS    36                     // cmp LDS quarter stride (floats)
#define RS    144                    // cmp LDS row stride
#define QP    136                    // K LDS row stride (bf16): pad 8
#define VP    72                     // VT/P LDS row stride (bf16): pad 8

typedef unsigned short ushort_t;
using bf16x8 = __attribute__((ext_vector_type(8))) short;
using f32x4  = __attribute__((ext_vector_type(4))) float;

__device__ __forceinline__ unsigned pkbf(float a, float b){
  union { __hip_bfloat162 h; unsigned u; } cv;
  cv.h = __float22bfloat162_rn(make_float2(a, b));
  return cv.u;
}
__device__ __forceinline__ ushort_t f2b(float f){
  union { float f; unsigned i; } x; x.f = f;
  unsigned r = x.i + 0x7fffu + ((x.i >> 16) & 1u);   // RNE
  return (ushort_t)(r >> 16);
}

// issue next phase's K/V loads into regs (kept in flight across compute)
__device__ __forceinline__ void issue_kv(const float* __restrict__ kb_,
                                         const float* __restrict__ vb_,
                                         int tid, float4 (&kr)[8], float4 (&vr)[8]){
#pragma unroll
  for (int jj = 0; jj < 8; ++jj){
    int i = tid + jj*256;
    int key = i >> 5, s4 = i & 31;
    kr[jj] = ((const float4*)(kb_ + (size_t)key*(KV*DIM)))[s4];
    int vkey = i & 63, f4 = i >> 6;
    vr[jj] = ((const float4*)(vb_ + (size_t)vkey*(KV*DIM)))[f4];
  }
}
// convert + commit regs into LDS (K row-major, V transposed)
__device__ __forceinline__ void commit_kv(int tid, const float4 (&kr)[8],
                                          const float4 (&vr)[8],
                                          short* Ks, short* VTs){
#pragma unroll
  for (int jj = 0; jj < 8; ++jj){
    int i = tid + jj*256;
    int key = i >> 5, s4 = i & 31;
    uint2 pk; pk.x = pkbf(kr[jj].x, kr[jj].y); pk.y = pkbf(kr[jj].z, kr[jj].w);
    *(uint2*)&Ks[key*QP + s4*4] = pk;
    int vkey = i & 63, f4 = i >> 6;
    unsigned p01 = pkbf(vr[jj].x, vr[jj].y), p23 = pkbf(vr[jj].z, vr[jj].w);
    VTs[(f4*4+0)*VP + vkey] = (short)(p01 & 0xffffu);
    VTs[(f4*4+1)*VP + vkey] = (short)(p01 >> 16);
    VTs[(f4*4+2)*VP + vkey] = (short)(p23 & 0xffffu);
    VTs[(f4*4+3)*VP + vkey] = (short)(p23 >> 16);
  }
}

// ---------------- kernel 1: block compression (coalesced, 256 blocks) -------
__global__ __launch_bounds__(256) void compress_k(
    const float* __restrict__ k, const float* __restrict__ v,
    const float* __restrict__ w_k, const float* __restrict__ b_k,
    const float* __restrict__ w_v, const float* __restrict__ b_v,
    float* __restrict__ Kc, float* __restrict__ Vc)
{
  int blk = blockIdx.x;            // (bb,g,n,dhalf)
  int dh = blk & 1;
  int n  = (blk >> 1) & 31;
  int g  = (blk >> 6) & 1;
  int bb = blk >> 7;
  int tid = threadIdx.x;

  __shared__ float wks[64], wvs[64];
  __shared__ float accK[16][64], accV[16][64];
  if (tid < 64){ wks[tid] = w_k[tid]; wvs[tid] = w_v[tid]; }
  __syncthreads();

  int r4 = tid >> 4, dq = tid & 15;
  float4 sk = {0,0,0,0}, sv = {0,0,0,0};
  for (int rr = 0; rr < 4; ++rr){
    int row = r4*4 + rr;
    size_t off = ((size_t)(bb*SEQ + n*64 + row)*KV + g)*DIM + dh*64 + dq*4;
    float4 kx = *(const float4*)(k + off);
    float4 vx = *(const float4*)(v + off);
    float a = wks[row], b = wvs[row];
    sk.x += a*kx.x; sk.y += a*kx.y; sk.z += a*kx.z; sk.w += a*kx.w;
    sv.x += b*vx.x; sv.y += b*vx.y; sv.z += b*vx.z; sv.w += b*vx.w;
  }
  *(float4*)&accK[r4][dq*4] = sk;
  *(float4*)&accV[r4][dq*4] = sv;
  __syncthreads();
  size_t obase = ((size_t)((bb*KV+g)*NBLK + n))*DIM + dh*64;
  if (tid < 64){
    float s = 0.f;
#pragma unroll
    for (int i = 0; i < 16; ++i) s += accK[i][tid];
    Kc[obase + tid] = s + b_k[0];
  } else if (tid < 128){
    int d = tid - 64;
    float s = 0.f;
#pragma unroll
    for (int i = 0; i < 16; ++i) s += accV[i][d];
    Vc[obase + d] = s + b_v[0];
  }
}

// ------- kernel 2: compressed attention (fp32 VALU; exact pooled P) ---------
__global__ __launch_bounds__(256) void cmp_attn_k(
    const float* __restrict__ q, const float* __restrict__ Kc,
    const float* __restrict__ Vc,
    const float* __restrict__ w_gate, const float* __restrict__ b_gate,
    float* __restrict__ pooled_part, float* __restrict__ out)
{
  int blk = blockIdx.x;
  int h  = blk & 3;
  int qb = (blk >> 2) & (NQB-1);
  int g  = (blk >> 7) & 1;
  int bb = blk >> 8;
  int tid = threadIdx.x;
  int qi = tid >> 2, c = tid & 3;

  __shared__ float Ks[32*RS];
  __shared__ float Vs[32*RS];
  __shared__ float wsum[4][NBLK];

  const float4* Ksrc = (const float4*)(Kc + (size_t)(bb*KV + g) * NBLK * DIM);
  const float4* Vsrc = (const float4*)(Vc + (size_t)(bb*KV + g) * NBLK * DIM);
  for (int i = tid; i < 1024; i += 256){
    int row = i >> 5, seg = i & 31;
    int dst = row*RS + (seg>>3)*QS + (seg&7)*4;
    ((float4*)(Ks+dst))[0] = Ksrc[i];
    ((float4*)(Vs+dst))[0] = Vsrc[i];
  }
  __syncthreads();

  int row = bb*SEQ + qb*64 + qi;
  float qv[32];
  {
    const float4* q4 = (const float4*)(q + ((size_t)row*QH + g*NH + h)*DIM + c*32);
#pragma unroll
    for (int j = 0; j < 8; ++j){
      float4 u = q4[j];
      qv[4*j+0]=u.x; qv[4*j+1]=u.y; qv[4*j+2]=u.z; qv[4*j+3]=u.w;
    }
  }

  float gp = 0.f;
#pragma unroll
  for (int d = 0; d < 32; ++d) gp += qv[d]*w_gate[(c*32+d)*3 + 0];
  gp += __shfl_xor(gp, 1); gp += __shfl_xor(gp, 2);
  float g0 = 1.f/(1.f + expf(-(gp + b_gate[0])));

  float sc[NBLK];
#pragma unroll
  for (int n = 0; n < NBLK; ++n){
    float p = 0.f;
    const float4* kr = (const float4*)(Ks + n*RS + c*QS);
#pragma unroll
    for (int j = 0; j < 8; ++j){
      float4 u = kr[j];
      p += qv[4*j+0]*u.x + qv[4*j+1]*u.y + qv[4*j+2]*u.z + qv[4*j+3]*u.w;
    }
    p += __shfl_xor(p, 1); p += __shfl_xor(p, 2);
    sc[n] = p * SCALE;
  }
  float m = sc[0];
#pragma unroll
  for (int n = 1; n < NBLK; ++n) m = fmaxf(m, sc[n]);
  float l = 0.f;
#pragma unroll
  for (int n = 0; n < NBLK; ++n){ sc[n] = expf(sc[n]-m); l += sc[n]; }
  float inv = 1.f/l;
#pragma unroll
  for (int n = 0; n < NBLK; ++n) sc[n] *= inv;

#pragma unroll
  for (int n = 0; n < NBLK; ++n){
    float t2 = sc[n];
    t2 += __shfl_xor(t2, 4); t2 += __shfl_xor(t2, 8);
    t2 += __shfl_xor(t2, 16); t2 += __shfl_xor(t2, 32);
    if ((tid & 63) == 0) wsum[tid>>6][n] = t2;
  }
  __syncthreads();
  if (tid < NBLK)
    pooled_part[(size_t)blk*NBLK + tid] =
        (wsum[0][tid]+wsum[1][tid]) + (wsum[2][tid]+wsum[3][tid]);

  float o[32];
#pragma unroll
  for (int d = 0; d < 32; ++d) o[d] = 0.f;
#pragma unroll
  for (int n = 0; n < NBLK; ++n){
    float pb = sc[n];
    const float4* vr = (const float4*)(Vs + n*RS + c*QS);
#pragma unroll
    for (int j = 0; j < 8; ++j){
      float4 u = vr[j];
      o[4*j+0] += pb*u.x; o[4*j+1] += pb*u.y;
      o[4*j+2] += pb*u.z; o[4*j+3] += pb*u.w;
    }
  }
  float* op = out + ((size_t)row*QH + g*NH + h)*DIM + c*32;
#pragma unroll
  for (int d = 0; d < 32; ++d) op[d] = g0*o[d];   // overwrite (first branch)
}

// ---- kernel 3: role-split topk+slc | win attention (MFMA, prefetch) --------
// grid 1024; idx&7 encodes (bb,g) twice -> same-(bb,g) blocks share XCDs.
// Layouts (m89/m91/m120): A[m=lane&15][k=quad*8+j], B[k=quad*8+j][n=lane&15],
// C[col=lane&15,row=quad*4+r]
__global__ __launch_bounds__(256, 3) void attn_k(
    const float* __restrict__ q, const float* __restrict__ k,
    const float* __restrict__ v, const float* __restrict__ pp,
    const float* __restrict__ w_gate, const float* __restrict__ b_gate,
    float* __restrict__ out)
{
  int idx = blockIdx.x;
  int x = idx & 7, low = idx & 1, u = idx >> 3;
  int bbg = x >> 1;                 // (bb,g)
  int j = u*2 + low;                // 0..255
  int role = j >> 7;                // 0 = slc, 1 = win
  int qb = (j >> 2) & 31;
  int h  = j & 3;
  int bb = bbg >> 1, g = bbg & 1;

  int tid = threadIdx.x;
  int lane = tid & 63, w = tid >> 6, quad = lane >> 4, l15 = lane & 15;

  __shared__ short Ks[64*QP];     // 17.0 KB
  __shared__ short VTs[128*VP];   // 18.0 KB
  __shared__ short Ps[64*VP];     //  9.0 KB
  __shared__ float gbuf[64];
  __shared__ int   idxs[NTOP];

  // ---- top-k (role 0 only; wave 0; lax.top_k tie rule) ----
  if (role == 0 && tid < 64){
    int n = lane;
    float val = -INFINITY;
    if (n < NBLK){
      const float* p0 = pp + ((size_t)((bb*KV+g)*NQB + qb)*NH)*NBLK + n;
      val = (p0[0] + p0[NBLK]) + (p0[2*NBLK] + p0[3*NBLK]);
    }
    for (int t = 0; t < NTOP; ++t){
      float bv = val; int bi = n;
      for (int mm = 1; mm < 32; mm <<= 1){
        float ov = __shfl_xor(bv, mm);
        int   oi = __shfl_xor(bi, mm);
        if (ov > bv || (ov == bv && oi < bi)){ bv = ov; bi = oi; }
      }
      if (lane == 0) idxs[t] = bi;
      if (n == bi) val = -INFINITY;
    }
  }

  // ---- Q fragments direct from global + exact fp32 gate (role-selected) ----
  const float* qrow = q + ((size_t)(bb*SEQ + qb*64 + w*16 + l15)*QH + g*NH + h)*DIM;
  int gcol = 1 + role;
  bf16x8 qfrag[4];
  float gp = 0.f;
#pragma unroll
  for (int kc = 0; kc < 4; ++kc){
    int d0 = kc*32 + quad*8;
    float4 u0 = *(const float4*)(qrow + d0);
    float4 u1 = *(const float4*)(qrow + d0 + 4);
    float qf[8] = {u0.x,u0.y,u0.z,u0.w,u1.x,u1.y,u1.z,u1.w};
#pragma unroll
    for (int jj = 0; jj < 8; ++jj) gp += qf[jj]*w_gate[(d0+jj)*3 + gcol];
    union { unsigned uu[4]; bf16x8 v8; } tq;
    tq.uu[0] = pkbf(u0.x,u0.y); tq.uu[1] = pkbf(u0.z,u0.w);
    tq.uu[2] = pkbf(u1.x,u1.y); tq.uu[3] = pkbf(u1.z,u1.w);
    qfrag[kc] = tq.v8;
  }
  gp += __shfl_xor(gp,16); gp += __shfl_xor(gp,32);
  if (quad == 0) gbuf[w*16+l15] = 1.f/(1.f + __expf(-(gp + b_gate[gcol])));
  __syncthreads();   // publishes gbuf + idxs
  float gl[4];
#pragma unroll
  for (int r = 0; r < 4; ++r) gl[r] = gbuf[w*16+quad*4+r];

  const float* kbase = k + ((size_t)(bb*SEQ)*KV + g)*DIM;
  const float* vbase = v + ((size_t)(bb*SEQ)*KV + g)*DIM;

  int kb0 = (qb >= 8) ? (qb - 8) : 0;
  int nph = (role == 0) ? NTOP : (qb - kb0 + 1);

  float m1[4], l1[4];
  f32x4 oacc[8];
  const f32x4 zero4 = {0.f,0.f,0.f,0.f};
#pragma unroll
  for (int r = 0; r < 4; ++r){ m1[r] = -INFINITY; l1[r] = 0.f; }
#pragma unroll
  for (int dt = 0; dt < 8; ++dt) oacc[dt] = zero4;

  float4 kreg[8], vreg[8];
  {
    int b0 = (role == 0) ? idxs[0] : kb0;
    issue_kv(kbase + (size_t)b0*64*KV*DIM, vbase + (size_t)b0*64*KV*DIM,
             tid, kreg, vreg);
  }

  for (int t = 0; t < nph; ++t){
    int kb = (role == 0) ? idxs[t] : (kb0 + t);
    __syncthreads();                       // consumers of phase t-1 done
    commit_kv(tid, kreg, vreg, Ks, VTs);   // cvt + LDS write
    __syncthreads();                       // LDS ready
    if (t + 1 < nph){                      // prefetch next phase (overlaps MFMA)
      int bn = (role == 0) ? idxs[t+1] : (kb0 + t + 1);
      issue_kv(kbase + (size_t)bn*64*KV*DIM, vbase + (size_t)bn*64*KV*DIM,
               tid, kreg, vreg);
    }

    f32x4 sacc[4];
#pragma unroll
    for (int nt = 0; nt < 4; ++nt) sacc[nt] = zero4;
#pragma unroll
    for (int kc = 0; kc < 4; ++kc){
      bf16x8 a = qfrag[kc];
#pragma unroll
      for (int nt = 0; nt < 4; ++nt){
        bf16x8 b = *(bf16x8*)&Ks[(nt*16 + l15)*QP + kc*32 + quad*8];
        sacc[nt] = __builtin_amdgcn_mfma_f32_16x16x32_bf16(a, b, sacc[nt], 0, 0, 0);
      }
    }

    bool mlow  = (role == 1) && (kb == qb - 8);   // valid: key >= qi
    bool mhigh = (role == 1) && (kb == qb);       // valid: key <= qi
    float alpha[4];
#pragma unroll
    for (int r = 0; r < 4; ++r){
      int qi_local = w*16 + quad*4 + r;
      float mx = -INFINITY;
#pragma unroll
      for (int nt = 0; nt < 4; ++nt){
        int key = nt*16 + l15;
        float sv = sacc[nt][r]*SCALE;
        bool valid = (!mlow || key >= qi_local) && (!mhigh || key <= qi_local);
        sv = valid ? sv : -INFINITY;
        sacc[nt][r] = sv;
        mx = fmaxf(mx, sv);
      }
      mx = fmaxf(mx, __shfl_xor(mx,1)); mx = fmaxf(mx, __shfl_xor(mx,2));
      mx = fmaxf(mx, __shfl_xor(mx,4)); mx = fmaxf(mx, __shfl_xor(mx,8));
      float mn = fmaxf(m1[r], mx);
      alpha[r] = __expf(m1[r] - mn);
      float s0 = 0.f;
#pragma unroll
      for (int nt = 0; nt < 4; ++nt){
        float pe = __expf(sacc[nt][r] - mn);   // masked -> 0
        sacc[nt][r] = pe;
        s0 += pe;
      }
      s0 += __shfl_xor(s0,1); s0 += __shfl_xor(s0,2);
      s0 += __shfl_xor(s0,4); s0 += __shfl_xor(s0,8);
      l1[r] = l1[r]*alpha[r] + s0;
      m1[r] = mn;
    }
    // P: C-layout -> LDS row-major; wave-private round trip
#pragma unroll
    for (int nt = 0; nt < 4; ++nt)
#pragma unroll
      for (int r = 0; r < 4; ++r)
        Ps[(w*16 + quad*4 + r)*VP + nt*16 + l15] = (short)f2b(sacc[nt][r]);
#pragma unroll
    for (int dt = 0; dt < 8; ++dt)
#pragma unroll
      for (int r = 0; r < 4; ++r) oacc[dt][r] *= alpha[r];
#pragma unroll
    for (int kc2 = 0; kc2 < 2; ++kc2){
      bf16x8 pa = *(bf16x8*)&Ps[(w*16 + l15)*VP + kc2*32 + quad*8];
#pragma unroll
      for (int dt = 0; dt < 8; ++dt){
        bf16x8 vb8 = *(bf16x8*)&VTs[(dt*16 + l15)*VP + kc2*32 + quad*8];
        oacc[dt] = __builtin_amdgcn_mfma_f32_16x16x32_bf16(pa, vb8, oacc[dt], 0, 0, 0);
      }
    }
  }

  // ---- epilogue: out += gate * branch / l  (atomic; slc/win may interleave)
#pragma unroll
  for (int r = 0; r < 4; ++r){
    float s2 = gl[r] / l1[r];
    float* op = out + ((size_t)(bb*SEQ + qb*64 + w*16 + quad*4 + r)*QH + g*NH + h)*DIM + l15;
#pragma unroll
    for (int dt = 0; dt < 8; ++dt)
      atomicAdd(&op[dt*16], s2 * oacc[dt][r]);
  }
}

extern "C" void kernel_launch(void* const* d_in, const int* in_sizes, int n_in,
                              void* d_out, int out_size, void* d_ws, size_t ws_size,
                              hipStream_t stream) {
  const float* q      = (const float*)d_in[0];
  const float* k      = (const float*)d_in[1];
  const float* v      = (const float*)d_in[2];
  const float* w_k    = (const float*)d_in[3];
  const float* b_k    = (const float*)d_in[4];
  const float* w_v    = (const float*)d_in[5];
  const float* b_v    = (const float*)d_in[6];
  const float* w_gate = (const float*)d_in[7];
  const float* b_gate = (const float*)d_in[8];
  float* out = (float*)d_out;

  float* ws = (float*)d_ws;
  float* Kc = ws;                     // 16384 f32
  float* Vc = ws + 16384;             // 16384 f32
  float* pp = ws + 32768;             // 512*32 f32 (per-head pooled partials)

  compress_k<<<256, 256, 0, stream>>>(k, v, w_k, b_k, w_v, b_v, Kc, Vc);
  cmp_attn_k<<<NB*KV*NQB*NH, 256, 0, stream>>>(q, Kc, Vc, w_gate, b_gate, pp, out);
  attn_k    <<<1024, 256, 0, stream>>>(q, k, v, pp, w_gate, b_gate, out);
}

// Round 9
// 367.109 us; speedup vs baseline: 1.0831x; 1.0831x over previous
//
#include <hip/hip_runtime.h>
#include <hip/hip_bf16.h>

// NSA forward, MI355X round 9. All inputs fp32, output fp32.
// r8 structure (role-split grid 1024, 3 blocks/CU, reg prefetch, XCD swizzle)
// with the atomic epilogue replaced by race-free plain stores:
//   win blocks RMW out (unique writer per location, after cmp),
//   slc blocks store to ws slcbuf, merge kernel adds it in.
// Shapes: S=4096, seqlen=2048, qh=8, kvh=2, dim=128, blk=64, TOPK=16,
// window=(512,0).

#define SEQ   2048
#define NB    2
#define KV    2
#define NH    4
#define QH    8
#define DIM   128
#define NBLK  32
#define NQB   32
#define NTOP  16
#define SCALE 0.08838834764831845f   // 128^-0.5
#define QS    36                     // cmp LDS quarter stride (floats)
#define RS    144                    // cmp LDS row stride
#define QP    136                    // K LDS row stride (bf16): pad 8
#define VP    72                     // VT/P LDS row stride (bf16): pad 8

typedef unsigned short ushort_t;
using bf16x8 = __attribute__((ext_vector_type(8))) short;
using f32x4  = __attribute__((ext_vector_type(4))) float;

__device__ __forceinline__ unsigned pkbf(float a, float b){
  union { __hip_bfloat162 h; unsigned u; } cv;
  cv.h = __float22bfloat162_rn(make_float2(a, b));
  return cv.u;
}
__device__ __forceinline__ ushort_t f2b(float f){
  union { float f; unsigned i; } x; x.f = f;
  unsigned r = x.i + 0x7fffu + ((x.i >> 16) & 1u);   // RNE
  return (ushort_t)(r >> 16);
}

// issue next phase's K/V loads into regs (kept in flight across compute)
__device__ __forceinline__ void issue_kv(const float* __restrict__ kb_,
                                         const float* __restrict__ vb_,
                                         int tid, float4 (&kr)[8], float4 (&vr)[8]){
#pragma unroll
  for (int jj = 0; jj < 8; ++jj){
    int i = tid + jj*256;
    int key = i >> 5, s4 = i & 31;
    kr[jj] = ((const float4*)(kb_ + (size_t)key*(KV*DIM)))[s4];
    int vkey = i & 63, f4 = i >> 6;
    vr[jj] = ((const float4*)(vb_ + (size_t)vkey*(KV*DIM)))[f4];
  }
}
// convert + commit regs into LDS (K row-major, V transposed)
__device__ __forceinline__ void commit_kv(int tid, const float4 (&kr)[8],
                                          const float4 (&vr)[8],
                                          short* Ks, short* VTs){
#pragma unroll
  for (int jj = 0; jj < 8; ++jj){
    int i = tid + jj*256;
    int key = i >> 5, s4 = i & 31;
    uint2 pk; pk.x = pkbf(kr[jj].x, kr[jj].y); pk.y = pkbf(kr[jj].z, kr[jj].w);
    *(uint2*)&Ks[key*QP + s4*4] = pk;
    int vkey = i & 63, f4 = i >> 6;
    unsigned p01 = pkbf(vr[jj].x, vr[jj].y), p23 = pkbf(vr[jj].z, vr[jj].w);
    VTs[(f4*4+0)*VP + vkey] = (short)(p01 & 0xffffu);
    VTs[(f4*4+1)*VP + vkey] = (short)(p01 >> 16);
    VTs[(f4*4+2)*VP + vkey] = (short)(p23 & 0xffffu);
    VTs[(f4*4+3)*VP + vkey] = (short)(p23 >> 16);
  }
}

// ---------------- kernel 1: block compression (coalesced, 256 blocks) -------
__global__ __launch_bounds__(256) void compress_k(
    const float* __restrict__ k, const float* __restrict__ v,
    const float* __restrict__ w_k, const float* __restrict__ b_k,
    const float* __restrict__ w_v, const float* __restrict__ b_v,
    float* __restrict__ Kc, float* __restrict__ Vc)
{
  int blk = blockIdx.x;            // (bb,g,n,dhalf)
  int dh = blk & 1;
  int n  = (blk >> 1) & 31;
  int g  = (blk >> 6) & 1;
  int bb = blk >> 7;
  int tid = threadIdx.x;

  __shared__ float wks[64], wvs[64];
  __shared__ float accK[16][64], accV[16][64];
  if (tid < 64){ wks[tid] = w_k[tid]; wvs[tid] = w_v[tid]; }
  __syncthreads();

  int r4 = tid >> 4, dq = tid & 15;
  float4 sk = {0,0,0,0}, sv = {0,0,0,0};
  for (int rr = 0; rr < 4; ++rr){
    int row = r4*4 + rr;
    size_t off = ((size_t)(bb*SEQ + n*64 + row)*KV + g)*DIM + dh*64 + dq*4;
    float4 kx = *(const float4*)(k + off);
    float4 vx = *(const float4*)(v + off);
    float a = wks[row], b = wvs[row];
    sk.x += a*kx.x; sk.y += a*kx.y; sk.z += a*kx.z; sk.w += a*kx.w;
    sv.x += b*vx.x; sv.y += b*vx.y; sv.z += b*vx.z; sv.w += b*vx.w;
  }
  *(float4*)&accK[r4][dq*4] = sk;
  *(float4*)&accV[r4][dq*4] = sv;
  __syncthreads();
  size_t obase = ((size_t)((bb*KV+g)*NBLK + n))*DIM + dh*64;
  if (tid < 64){
    float s = 0.f;
#pragma unroll
    for (int i = 0; i < 16; ++i) s += accK[i][tid];
    Kc[obase + tid] = s + b_k[0];
  } else if (tid < 128){
    int d = tid - 64;
    float s = 0.f;
#pragma unroll
    for (int i = 0; i < 16; ++i) s += accV[i][d];
    Vc[obase + d] = s + b_v[0];
  }
}

// ------- kernel 2: compressed attention (fp32 VALU; exact pooled P) ---------
__global__ __launch_bounds__(256) void cmp_attn_k(
    const float* __restrict__ q, const float* __restrict__ Kc,
    const float* __restrict__ Vc,
    const float* __restrict__ w_gate, const float* __restrict__ b_gate,
    float* __restrict__ pooled_part, float* __restrict__ out)
{
  int blk = blockIdx.x;
  int h  = blk & 3;
  int qb = (blk >> 2) & (NQB-1);
  int g  = (blk >> 7) & 1;
  int bb = blk >> 8;
  int tid = threadIdx.x;
  int qi = tid >> 2, c = tid & 3;

  __shared__ float Ks[32*RS];
  __shared__ float Vs[32*RS];
  __shared__ float wsum[4][NBLK];

  const float4* Ksrc = (const float4*)(Kc + (size_t)(bb*KV + g) * NBLK * DIM);
  const float4* Vsrc = (const float4*)(Vc + (size_t)(bb*KV + g) * NBLK * DIM);
  for (int i = tid; i < 1024; i += 256){
    int row = i >> 5, seg = i & 31;
    int dst = row*RS + (seg>>3)*QS + (seg&7)*4;
    ((float4*)(Ks+dst))[0] = Ksrc[i];
    ((float4*)(Vs+dst))[0] = Vsrc[i];
  }
  __syncthreads();

  int row = bb*SEQ + qb*64 + qi;
  float qv[32];
  {
    const float4* q4 = (const float4*)(q + ((size_t)row*QH + g*NH + h)*DIM + c*32);
#pragma unroll
    for (int j = 0; j < 8; ++j){
      float4 u = q4[j];
      qv[4*j+0]=u.x; qv[4*j+1]=u.y; qv[4*j+2]=u.z; qv[4*j+3]=u.w;
    }
  }

  float gp = 0.f;
#pragma unroll
  for (int d = 0; d < 32; ++d) gp += qv[d]*w_gate[(c*32+d)*3 + 0];
  gp += __shfl_xor(gp, 1); gp += __shfl_xor(gp, 2);
  float g0 = 1.f/(1.f + expf(-(gp + b_gate[0])));

  float sc[NBLK];
#pragma unroll
  for (int n = 0; n < NBLK; ++n){
    float p = 0.f;
    const float4* kr = (const float4*)(Ks + n*RS + c*QS);
#pragma unroll
    for (int j = 0; j < 8; ++j){
      float4 u = kr[j];
      p += qv[4*j+0]*u.x + qv[4*j+1]*u.y + qv[4*j+2]*u.z + qv[4*j+3]*u.w;
    }
    p += __shfl_xor(p, 1); p += __shfl_xor(p, 2);
    sc[n] = p * SCALE;
  }
  float m = sc[0];
#pragma unroll
  for (int n = 1; n < NBLK; ++n) m = fmaxf(m, sc[n]);
  float l = 0.f;
#pragma unroll
  for (int n = 0; n < NBLK; ++n){ sc[n] = expf(sc[n]-m); l += sc[n]; }
  float inv = 1.f/l;
#pragma unroll
  for (int n = 0; n < NBLK; ++n) sc[n] *= inv;

#pragma unroll
  for (int n = 0; n < NBLK; ++n){
    float t2 = sc[n];
    t2 += __shfl_xor(t2, 4); t2 += __shfl_xor(t2, 8);
    t2 += __shfl_xor(t2, 16); t2 += __shfl_xor(t2, 32);
    if ((tid & 63) == 0) wsum[tid>>6][n] = t2;
  }
  __syncthreads();
  if (tid < NBLK)
    pooled_part[(size_t)blk*NBLK + tid] =
        (wsum[0][tid]+wsum[1][tid]) + (wsum[2][tid]+wsum[3][tid]);

  float o[32];
#pragma unroll
  for (int d = 0; d < 32; ++d) o[d] = 0.f;
#pragma unroll
  for (int n = 0; n < NBLK; ++n){
    float pb = sc[n];
    const float4* vr = (const float4*)(Vs + n*RS + c*QS);
#pragma unroll
    for (int j = 0; j < 8; ++j){
      float4 u = vr[j];
      o[4*j+0] += pb*u.x; o[4*j+1] += pb*u.y;
      o[4*j+2] += pb*u.z; o[4*j+3] += pb*u.w;
    }
  }
  float* op = out + ((size_t)row*QH + g*NH + h)*DIM + c*32;
#pragma unroll
  for (int d = 0; d < 32; ++d) op[d] = g0*o[d];   // overwrite (first branch)
}

// ---- kernel 3: role-split topk+slc | win attention (MFMA, prefetch) --------
// grid 1024; idx&7 encodes (bb,g) twice -> same-(bb,g) blocks share XCDs.
// Layouts (m89/m91/m120): A[m=lane&15][k=quad*8+j], B[k=quad*8+j][n=lane&15],
// C[col=lane&15,row=quad*4+r]
__global__ __launch_bounds__(256, 3) void attn_k(
    const float* __restrict__ q, const float* __restrict__ k,
    const float* __restrict__ v, const float* __restrict__ pp,
    const float* __restrict__ w_gate, const float* __restrict__ b_gate,
    float* __restrict__ slcbuf, float* __restrict__ out)
{
  int idx = blockIdx.x;
  int x = idx & 7, low = idx & 1, u = idx >> 3;
  int bbg = x >> 1;                 // (bb,g)
  int j = u*2 + low;                // 0..255
  int role = j >> 7;                // 0 = slc, 1 = win
  int qb = (j >> 2) & 31;
  int h  = j & 3;
  int bb = bbg >> 1, g = bbg & 1;

  int tid = threadIdx.x;
  int lane = tid & 63, w = tid >> 6, quad = lane >> 4, l15 = lane & 15;

  __shared__ short Ks[64*QP];     // 17.0 KB
  __shared__ short VTs[128*VP];   // 18.0 KB
  __shared__ short Ps[64*VP];     //  9.0 KB
  __shared__ float gbuf[64];
  __shared__ int   idxs[NTOP];

  // ---- top-k (role 0 only; wave 0; lax.top_k tie rule) ----
  if (role == 0 && tid < 64){
    int n = lane;
    float val = -INFINITY;
    if (n < NBLK){
      const float* p0 = pp + ((size_t)((bb*KV+g)*NQB + qb)*NH)*NBLK + n;
      val = (p0[0] + p0[NBLK]) + (p0[2*NBLK] + p0[3*NBLK]);
    }
    for (int t = 0; t < NTOP; ++t){
      float bv = val; int bi = n;
      for (int mm = 1; mm < 32; mm <<= 1){
        float ov = __shfl_xor(bv, mm);
        int   oi = __shfl_xor(bi, mm);
        if (ov > bv || (ov == bv && oi < bi)){ bv = ov; bi = oi; }
      }
      if (lane == 0) idxs[t] = bi;
      if (n == bi) val = -INFINITY;
    }
  }

  // ---- Q fragments direct from global + exact fp32 gate (role-selected) ----
  const float* qrow = q + ((size_t)(bb*SEQ + qb*64 + w*16 + l15)*QH + g*NH + h)*DIM;
  int gcol = 1 + role;
  bf16x8 qfrag[4];
  float gp = 0.f;
#pragma unroll
  for (int kc = 0; kc < 4; ++kc){
    int d0 = kc*32 + quad*8;
    float4 u0 = *(const float4*)(qrow + d0);
    float4 u1 = *(const float4*)(qrow + d0 + 4);
    float qf[8] = {u0.x,u0.y,u0.z,u0.w,u1.x,u1.y,u1.z,u1.w};
#pragma unroll
    for (int jj = 0; jj < 8; ++jj) gp += qf[jj]*w_gate[(d0+jj)*3 + gcol];
    union { unsigned uu[4]; bf16x8 v8; } tq;
    tq.uu[0] = pkbf(u0.x,u0.y); tq.uu[1] = pkbf(u0.z,u0.w);
    tq.uu[2] = pkbf(u1.x,u1.y); tq.uu[3] = pkbf(u1.z,u1.w);
    qfrag[kc] = tq.v8;
  }
  gp += __shfl_xor(gp,16); gp += __shfl_xor(gp,32);
  if (quad == 0) gbuf[w*16+l15] = 1.f/(1.f + __expf(-(gp + b_gate[gcol])));
  __syncthreads();   // publishes gbuf + idxs
  float gl[4];
#pragma unroll
  for (int r = 0; r < 4; ++r) gl[r] = gbuf[w*16+quad*4+r];

  const float* kbase = k + ((size_t)(bb*SEQ)*KV + g)*DIM;
  const float* vbase = v + ((size_t)(bb*SEQ)*KV + g)*DIM;

  int kb0 = (qb >= 8) ? (qb - 8) : 0;
  int nph = (role == 0) ? NTOP : (qb - kb0 + 1);

  float m1[4], l1[4];
  f32x4 oacc[8];
  const f32x4 zero4 = {0.f,0.f,0.f,0.f};
#pragma unroll
  for (int r = 0; r < 4; ++r){ m1[r] = -INFINITY; l1[r] = 0.f; }
#pragma unroll
  for (int dt = 0; dt < 8; ++dt) oacc[dt] = zero4;

  float4 kreg[8], vreg[8];
  {
    int b0 = (role == 0) ? idxs[0] : kb0;
    issue_kv(kbase + (size_t)b0*64*KV*DIM, vbase + (size_t)b0*64*KV*DIM,
             tid, kreg, vreg);
  }

  for (int t = 0; t < nph; ++t){
    int kb = (role == 0) ? idxs[t] : (kb0 + t);
    __syncthreads();                       // consumers of phase t-1 done
    commit_kv(tid, kreg, vreg, Ks, VTs);   // cvt + LDS write
    __syncthreads();                       // LDS ready
    if (t + 1 < nph){                      // prefetch next phase (overlaps MFMA)
      int bn = (role == 0) ? idxs[t+1] : (kb0 + t + 1);
      issue_kv(kbase + (size_t)bn*64*KV*DIM, vbase + (size_t)bn*64*KV*DIM,
               tid, kreg, vreg);
    }

    f32x4 sacc[4];
#pragma unroll
    for (int nt = 0; nt < 4; ++nt) sacc[nt] = zero4;
#pragma unroll
    for (int kc = 0; kc < 4; ++kc){
      bf16x8 a = qfrag[kc];
#pragma unroll
      for (int nt = 0; nt < 4; ++nt){
        bf16x8 b = *(bf16x8*)&Ks[(nt*16 + l15)*QP + kc*32 + quad*8];
        sacc[nt] = __builtin_amdgcn_mfma_f32_16x16x32_bf16(a, b, sacc[nt], 0, 0, 0);
      }
    }

    bool mlow  = (role == 1) && (kb == qb - 8);   // valid: key >= qi
    bool mhigh = (role == 1) && (kb == qb);       // valid: key <= qi
    float alpha[4];
#pragma unroll
    for (int r = 0; r < 4; ++r){
      int qi_local = w*16 + quad*4 + r;
      float mx = -INFINITY;
#pragma unroll
      for (int nt = 0; nt < 4; ++nt){
        int key = nt*16 + l15;
        float sv = sacc[nt][r]*SCALE;
        bool valid = (!mlow || key >= qi_local) && (!mhigh || key <= qi_local);
        sv = valid ? sv : -INFINITY;
        sacc[nt][r] = sv;
        mx = fmaxf(mx, sv);
      }
      mx = fmaxf(mx, __shfl_xor(mx,1)); mx = fmaxf(mx, __shfl_xor(mx,2));
      mx = fmaxf(mx, __shfl_xor(mx,4)); mx = fmaxf(mx, __shfl_xor(mx,8));
      float mn = fmaxf(m1[r], mx);
      alpha[r] = __expf(m1[r] - mn);
      float s0 = 0.f;
#pragma unroll
      for (int nt = 0; nt < 4; ++nt){
        float pe = __expf(sacc[nt][r] - mn);   // masked -> 0
        sacc[nt][r] = pe;
        s0 += pe;
      }
      s0 += __shfl_xor(s0,1); s0 += __shfl_xor(s0,2);
      s0 += __shfl_xor(s0,4); s0 += __shfl_xor(s0,8);
      l1[r] = l1[r]*alpha[r] + s0;
      m1[r] = mn;
    }
    // P: C-layout -> LDS row-major; wave-private round trip
#pragma unroll
    for (int nt = 0; nt < 4; ++nt)
#pragma unroll
      for (int r = 0; r < 4; ++r)
        Ps[(w*16 + quad*4 + r)*VP + nt*16 + l15] = (short)f2b(sacc[nt][r]);
#pragma unroll
    for (int dt = 0; dt < 8; ++dt)
#pragma unroll
      for (int r = 0; r < 4; ++r) oacc[dt][r] *= alpha[r];
#pragma unroll
    for (int kc2 = 0; kc2 < 2; ++kc2){
      bf16x8 pa = *(bf16x8*)&Ps[(w*16 + l15)*VP + kc2*32 + quad*8];
#pragma unroll
      for (int dt = 0; dt < 8; ++dt){
        bf16x8 vb8 = *(bf16x8*)&VTs[(dt*16 + l15)*VP + kc2*32 + quad*8];
        oacc[dt] = __builtin_amdgcn_mfma_f32_16x16x32_bf16(pa, vb8, oacc[dt], 0, 0, 0);
      }
    }
  }

  // ---- epilogue: race-free plain stores ----
#pragma unroll
  for (int r = 0; r < 4; ++r){
    float s2 = gl[r] / l1[r];
    size_t ob = ((size_t)(bb*SEQ + qb*64 + w*16 + quad*4 + r)*QH + g*NH + h)*DIM + l15;
    if (role == 0){
      float* op = slcbuf + ob;              // unique writer; full coverage
#pragma unroll
      for (int dt = 0; dt < 8; ++dt) op[dt*16] = s2 * oacc[dt][r];
    } else {
      float* op = out + ob;                 // unique writer; cmp already done
#pragma unroll
      for (int dt = 0; dt < 8; ++dt) op[dt*16] += s2 * oacc[dt][r];
    }
  }
}

// ---------------- kernel 4: merge (out += slcbuf) ---------------------------
__global__ __launch_bounds__(256) void merge_k(const float* __restrict__ slcbuf,
                                               float* __restrict__ out){
  int i = blockIdx.x * 256 + threadIdx.x;   // over 4096*8*128/4 float4s
  float4 a = ((const float4*)slcbuf)[i];
  float4 b = ((float4*)out)[i];
  b.x += a.x; b.y += a.y; b.z += a.z; b.w += a.w;
  ((float4*)out)[i] = b;
}

extern "C" void kernel_launch(void* const* d_in, const int* in_sizes, int n_in,
                              void* d_out, int out_size, void* d_ws, size_t ws_size,
                              hipStream_t stream) {
  const float* q      = (const float*)d_in[0];
  const float* k      = (const float*)d_in[1];
  const float* v      = (const float*)d_in[2];
  const float* w_k    = (const float*)d_in[3];
  const float* b_k    = (const float*)d_in[4];
  const float* w_v    = (const float*)d_in[5];
  const float* b_v    = (const float*)d_in[6];
  const float* w_gate = (const float*)d_in[7];
  const float* b_gate = (const float*)d_in[8];
  float* out = (float*)d_out;

  float* ws     = (float*)d_ws;
  float* Kc     = ws;                  // 16384 f32
  float* Vc     = ws + 16384;          // 16384 f32
  float* pp     = ws + 32768;          // 512*32 f32
  float* slcbuf = ws + 49152;          // 4096*8*128 = 4.19M f32 (16.8 MB)

  compress_k<<<256, 256, 0, stream>>>(k, v, w_k, b_k, w_v, b_v, Kc, Vc);
  cmp_attn_k<<<NB*KV*NQB*NH, 256, 0, stream>>>(q, Kc, Vc, w_gate, b_gate, pp, out);
  attn_k    <<<1024, 256, 0, stream>>>(q, k, v, pp, w_gate, b_gate, slcbuf, out);
  merge_k   <<<4096, 256, 0, stream>>>(slcbuf, out);
}

// Round 10
// 198.601 us; speedup vs baseline: 2.0021x; 1.8485x over previous
//
#include <hip/hip_runtime.h>
#include <hip/hip_bf16.h>

// NSA forward, MI355X round 10. All inputs fp32, output fp32.
// r9 minus the spill: prep_k pre-converts K (bf16 row-major) and V (bf16
// TRANSPOSED) per (bb,g) into ws; attn_k staging is a pure 16B copy
// (no cvt, no scalar transpose, no held prefetch regs -> no scratch).
// Role-split grid 1024 (3 blocks/CU), XCD swizzle, slcbuf+merge epilogue.
// Shapes: S=4096, seqlen=2048, qh=8, kvh=2, dim=128, blk=64, TOPK=16,
// window=(512,0).

#define SEQ   2048
#define NB    2
#define KV    2
#define NH    4
#define QH    8
#define DIM   128
#define NBLK  32
#define NQB   32
#define NTOP  16
#define SCALE 0.08838834764831845f   // 128^-0.5
#define QS    36                     // cmp LDS quarter stride (floats)
#define RS    144                    // cmp LDS row stride
#define QP    136                    // K LDS row stride (bf16): pad 8
#define VP    72                     // VT/P LDS row stride (bf16): pad 8

typedef unsigned short ushort_t;
using bf16x8 = __attribute__((ext_vector_type(8))) short;
using f32x4  = __attribute__((ext_vector_type(4))) float;

__device__ __forceinline__ unsigned pkbf(float a, float b){
  union { __hip_bfloat162 h; unsigned u; } cv;
  cv.h = __float22bfloat162_rn(make_float2(a, b));
  return cv.u;
}
__device__ __forceinline__ ushort_t f2b(float f){
  union { float f; unsigned i; } x; x.f = f;
  unsigned r = x.i + 0x7fffu + ((x.i >> 16) & 1u);   // RNE
  return (ushort_t)(r >> 16);
}

// ---------------- kernel 0: K/V bf16 preprocessing --------------------------
// Kb[(bbg*SEQ + row)*DIM + d] (row-major bf16); VT[(bbg*DIM + d)*SEQ + row]
// (transposed bf16 via LDS tile). grid 256 = bbg(4) x rowblk(32) x dhalf(2).
__global__ __launch_bounds__(256) void prep_k(
    const float* __restrict__ k, const float* __restrict__ v,
    ushort_t* __restrict__ Kb, ushort_t* __restrict__ VT)
{
  int blk = blockIdx.x;
  int db = blk & 1, rb = (blk >> 1) & 31, bbg = blk >> 6;
  int bb = bbg >> 1, g = bbg & 1;
  int tid = threadIdx.x;
  __shared__ ushort_t T[64*VP];    // [d 0..63][key 0..63], pad 8

  for (int jj = 0; jj < 4; ++jj){
    int i = tid + jj*256;                 // 1024 float4 units (64 rows x 16)
    int r = i >> 4, ds = i & 15;
    size_t src = ((size_t)(bb*SEQ + rb*64 + r)*KV + g)*DIM + db*64 + ds*4;
    float4 kx = *(const float4*)(k + src);
    float4 vx = *(const float4*)(v + src);
    uint2 kk; kk.x = pkbf(kx.x,kx.y); kk.y = pkbf(kx.z,kx.w);
    *(uint2*)&Kb[((size_t)bbg*SEQ + rb*64 + r)*DIM + db*64 + ds*4] = kk;
    unsigned v01 = pkbf(vx.x,vx.y), v23 = pkbf(vx.z,vx.w);
    T[(ds*4+0)*VP + r] = (ushort_t)(v01 & 0xffffu);
    T[(ds*4+1)*VP + r] = (ushort_t)(v01 >> 16);
    T[(ds*4+2)*VP + r] = (ushort_t)(v23 & 0xffffu);
    T[(ds*4+3)*VP + r] = (ushort_t)(v23 >> 16);
  }
  __syncthreads();
  for (int jj = 0; jj < 4; ++jj){
    int i = tid + jj*256;                 // 1024 8B units (64 d x 16)
    int d = i >> 4, seg = i & 15;
    uint2 u = *(uint2*)&T[d*VP + seg*4];
    *(uint2*)&VT[((size_t)bbg*DIM + db*64 + d)*SEQ + rb*64 + seg*4] = u;
  }
}

// ---------------- kernel 1: block compression (fp32 out to ws) --------------
__global__ __launch_bounds__(256) void compress_k(
    const float* __restrict__ k, const float* __restrict__ v,
    const float* __restrict__ w_k, const float* __restrict__ b_k,
    const float* __restrict__ w_v, const float* __restrict__ b_v,
    float* __restrict__ Kc, float* __restrict__ Vc)
{
  int blk = blockIdx.x;            // (bb,g,n,dhalf)
  int dh = blk & 1;
  int n  = (blk >> 1) & 31;
  int g  = (blk >> 6) & 1;
  int bb = blk >> 7;
  int tid = threadIdx.x;

  __shared__ float wks[64], wvs[64];
  __shared__ float accK[16][64], accV[16][64];
  if (tid < 64){ wks[tid] = w_k[tid]; wvs[tid] = w_v[tid]; }
  __syncthreads();

  int r4 = tid >> 4, dq = tid & 15;
  float4 sk = {0,0,0,0}, sv = {0,0,0,0};
  for (int rr = 0; rr < 4; ++rr){
    int row = r4*4 + rr;
    size_t off = ((size_t)(bb*SEQ + n*64 + row)*KV + g)*DIM + dh*64 + dq*4;
    float4 kx = *(const float4*)(k + off);
    float4 vx = *(const float4*)(v + off);
    float a = wks[row], b = wvs[row];
    sk.x += a*kx.x; sk.y += a*kx.y; sk.z += a*kx.z; sk.w += a*kx.w;
    sv.x += b*vx.x; sv.y += b*vx.y; sv.z += b*vx.z; sv.w += b*vx.w;
  }
  *(float4*)&accK[r4][dq*4] = sk;
  *(float4*)&accV[r4][dq*4] = sv;
  __syncthreads();
  size_t obase = ((size_t)((bb*KV+g)*NBLK + n))*DIM + dh*64;
  if (tid < 64){
    float s = 0.f;
#pragma unroll
    for (int i = 0; i < 16; ++i) s += accK[i][tid];
    Kc[obase + tid] = s + b_k[0];
  } else if (tid < 128){
    int d = tid - 64;
    float s = 0.f;
#pragma unroll
    for (int i = 0; i < 16; ++i) s += accV[i][d];
    Vc[obase + d] = s + b_v[0];
  }
}

// ------- kernel 2: compressed attention (fp32 VALU; exact pooled P) ---------
__global__ __launch_bounds__(256) void cmp_attn_k(
    const float* __restrict__ q, const float* __restrict__ Kc,
    const float* __restrict__ Vc,
    const float* __restrict__ w_gate, const float* __restrict__ b_gate,
    float* __restrict__ pooled_part, float* __restrict__ out)
{
  int blk = blockIdx.x;
  int h  = blk & 3;
  int qb = (blk >> 2) & (NQB-1);
  int g  = (blk >> 7) & 1;
  int bb = blk >> 8;
  int tid = threadIdx.x;
  int qi = tid >> 2, c = tid & 3;

  __shared__ float Ks[32*RS];
  __shared__ float Vs[32*RS];
  __shared__ float wsum[4][NBLK];

  const float4* Ksrc = (const float4*)(Kc + (size_t)(bb*KV + g) * NBLK * DIM);
  const float4* Vsrc = (const float4*)(Vc + (size_t)(bb*KV + g) * NBLK * DIM);
  for (int i = tid; i < 1024; i += 256){
    int row = i >> 5, seg = i & 31;
    int dst = row*RS + (seg>>3)*QS + (seg&7)*4;
    ((float4*)(Ks+dst))[0] = Ksrc[i];
    ((float4*)(Vs+dst))[0] = Vsrc[i];
  }
  __syncthreads();

  int row = bb*SEQ + qb*64 + qi;
  float qv[32];
  {
    const float4* q4 = (const float4*)(q + ((size_t)row*QH + g*NH + h)*DIM + c*32);
#pragma unroll
    for (int j = 0; j < 8; ++j){
      float4 u = q4[j];
      qv[4*j+0]=u.x; qv[4*j+1]=u.y; qv[4*j+2]=u.z; qv[4*j+3]=u.w;
    }
  }

  float gp = 0.f;
#pragma unroll
  for (int d = 0; d < 32; ++d) gp += qv[d]*w_gate[(c*32+d)*3 + 0];
  gp += __shfl_xor(gp, 1); gp += __shfl_xor(gp, 2);
  float g0 = 1.f/(1.f + expf(-(gp + b_gate[0])));

  float sc[NBLK];
#pragma unroll
  for (int n = 0; n < NBLK; ++n){
    float p = 0.f;
    const float4* kr = (const float4*)(Ks + n*RS + c*QS);
#pragma unroll
    for (int j = 0; j < 8; ++j){
      float4 u = kr[j];
      p += qv[4*j+0]*u.x + qv[4*j+1]*u.y + qv[4*j+2]*u.z + qv[4*j+3]*u.w;
    }
    p += __shfl_xor(p, 1); p += __shfl_xor(p, 2);
    sc[n] = p * SCALE;
  }
  float m = sc[0];
#pragma unroll
  for (int n = 1; n < NBLK; ++n) m = fmaxf(m, sc[n]);
  float l = 0.f;
#pragma unroll
  for (int n = 0; n < NBLK; ++n){ sc[n] = expf(sc[n]-m); l += sc[n]; }
  float inv = 1.f/l;
#pragma unroll
  for (int n = 0; n < NBLK; ++n) sc[n] *= inv;

#pragma unroll
  for (int n = 0; n < NBLK; ++n){
    float t2 = sc[n];
    t2 += __shfl_xor(t2, 4); t2 += __shfl_xor(t2, 8);
    t2 += __shfl_xor(t2, 16); t2 += __shfl_xor(t2, 32);
    if ((tid & 63) == 0) wsum[tid>>6][n] = t2;
  }
  __syncthreads();
  if (tid < NBLK)
    pooled_part[(size_t)blk*NBLK + tid] =
        (wsum[0][tid]+wsum[1][tid]) + (wsum[2][tid]+wsum[3][tid]);

  float o[32];
#pragma unroll
  for (int d = 0; d < 32; ++d) o[d] = 0.f;
#pragma unroll
  for (int n = 0; n < NBLK; ++n){
    float pb = sc[n];
    const float4* vr = (const float4*)(Vs + n*RS + c*QS);
#pragma unroll
    for (int j = 0; j < 8; ++j){
      float4 u = vr[j];
      o[4*j+0] += pb*u.x; o[4*j+1] += pb*u.y;
      o[4*j+2] += pb*u.z; o[4*j+3] += pb*u.w;
    }
  }
  float* op = out + ((size_t)row*QH + g*NH + h)*DIM + c*32;
#pragma unroll
  for (int d = 0; d < 32; ++d) op[d] = g0*o[d];   // overwrite (first branch)
}

// ---- kernel 3: role-split topk+slc | win attention (MFMA, copy staging) ----
// grid 1024; idx&7 encodes (bb,g) twice -> same-(bb,g) blocks share XCDs.
// Layouts (m89/m91/m120): A[m=lane&15][k=quad*8+j], B[k=quad*8+j][n=lane&15],
// C[col=lane&15,row=quad*4+r]
__global__ __launch_bounds__(256, 3) void attn_k(
    const float* __restrict__ q, const ushort_t* __restrict__ Kb,
    const ushort_t* __restrict__ VT, const float* __restrict__ pp,
    const float* __restrict__ w_gate, const float* __restrict__ b_gate,
    float* __restrict__ slcbuf, float* __restrict__ out)
{
  int idx = blockIdx.x;
  int x = idx & 7, low = idx & 1, u = idx >> 3;
  int bbg = x >> 1;                 // (bb,g)
  int j = u*2 + low;                // 0..255
  int role = j >> 7;                // 0 = slc, 1 = win
  int qb = (j >> 2) & 31;
  int h  = j & 3;
  int bb = bbg >> 1, g = bbg & 1;

  int tid = threadIdx.x;
  int lane = tid & 63, w = tid >> 6, quad = lane >> 4, l15 = lane & 15;

  __shared__ short Ks[64*QP];     // 17.0 KB
  __shared__ short VTs[128*VP];   // 18.0 KB
  __shared__ short Ps[64*VP];     //  9.0 KB
  __shared__ float gbuf[64];
  __shared__ int   idxs[NTOP];

  // ---- top-k (role 0 only; wave 0; lax.top_k tie rule) ----
  if (role == 0 && tid < 64){
    int n = lane;
    float val = -INFINITY;
    if (n < NBLK){
      const float* p0 = pp + ((size_t)((bb*KV+g)*NQB + qb)*NH)*NBLK + n;
      val = (p0[0] + p0[NBLK]) + (p0[2*NBLK] + p0[3*NBLK]);
    }
    for (int t = 0; t < NTOP; ++t){
      float bv = val; int bi = n;
      for (int mm = 1; mm < 32; mm <<= 1){
        float ov = __shfl_xor(bv, mm);
        int   oi = __shfl_xor(bi, mm);
        if (ov > bv || (ov == bv && oi < bi)){ bv = ov; bi = oi; }
      }
      if (lane == 0) idxs[t] = bi;
      if (n == bi) val = -INFINITY;
    }
  }

  // ---- Q fragments direct from global + exact fp32 gate (role-selected) ----
  const float* qrow = q + ((size_t)(bb*SEQ + qb*64 + w*16 + l15)*QH + g*NH + h)*DIM;
  int gcol = 1 + role;
  bf16x8 qfrag[4];
  float gp = 0.f;
#pragma unroll
  for (int kc = 0; kc < 4; ++kc){
    int d0 = kc*32 + quad*8;
    float4 u0 = *(const float4*)(qrow + d0);
    float4 u1 = *(const float4*)(qrow + d0 + 4);
    float qf[8] = {u0.x,u0.y,u0.z,u0.w,u1.x,u1.y,u1.z,u1.w};
#pragma unroll
    for (int jj = 0; jj < 8; ++jj) gp += qf[jj]*w_gate[(d0+jj)*3 + gcol];
    union { unsigned uu[4]; bf16x8 v8; } tq;
    tq.uu[0] = pkbf(u0.x,u0.y); tq.uu[1] = pkbf(u0.z,u0.w);
    tq.uu[2] = pkbf(u1.x,u1.y); tq.uu[3] = pkbf(u1.z,u1.w);
    qfrag[kc] = tq.v8;
  }
  gp += __shfl_xor(gp,16); gp += __shfl_xor(gp,32);
  if (quad == 0) gbuf[w*16+l15] = 1.f/(1.f + __expf(-(gp + b_gate[gcol])));
  __syncthreads();   // publishes gbuf + idxs
  float gl[4];
#pragma unroll
  for (int r = 0; r < 4; ++r) gl[r] = gbuf[w*16+quad*4+r];

  const ushort_t* kbase = Kb + (size_t)bbg*SEQ*DIM;
  const ushort_t* vtbase = VT + (size_t)bbg*DIM*SEQ;

  int kb0 = (qb >= 8) ? (qb - 8) : 0;
  int nph = (role == 0) ? NTOP : (qb - kb0 + 1);

  float m1[4], l1[4];
  f32x4 oacc[8];
  const f32x4 zero4 = {0.f,0.f,0.f,0.f};
#pragma unroll
  for (int r = 0; r < 4; ++r){ m1[r] = -INFINITY; l1[r] = 0.f; }
#pragma unroll
  for (int dt = 0; dt < 8; ++dt) oacc[dt] = zero4;

  for (int t = 0; t < nph; ++t){
    int kb = (role == 0) ? idxs[t] : (kb0 + t);
    __syncthreads();                       // phase t-1 consumers done
    // ---- staging: pure 16B copies (no cvt, no transpose) ----
    {
      const ushort_t* ksrc = kbase + (size_t)kb*64*DIM;
#pragma unroll
      for (int jj = 0; jj < 4; ++jj){      // K tile: 64 rows x 128 bf16
        int i = tid + jj*256;
        int row = i >> 4, seg = i & 15;
        uint4 uu = *(const uint4*)(ksrc + row*DIM + seg*8);
        *(uint4*)&Ks[row*QP + seg*8] = uu;
      }
      const ushort_t* vsrc = vtbase + kb*64;
#pragma unroll
      for (int jj = 0; jj < 4; ++jj){      // VT tile: 128 drows x 64 bf16
        int i = tid + jj*256;
        int dr = i >> 3, seg = i & 7;
        uint4 uu = *(const uint4*)(vsrc + (size_t)dr*SEQ + seg*8);
        *(uint4*)&VTs[dr*VP + seg*8] = uu;
      }
    }
    __syncthreads();                       // LDS ready

    f32x4 sacc[4];
#pragma unroll
    for (int nt = 0; nt < 4; ++nt) sacc[nt] = zero4;
#pragma unroll
    for (int kc = 0; kc < 4; ++kc){
      bf16x8 a = qfrag[kc];
#pragma unroll
      for (int nt = 0; nt < 4; ++nt){
        bf16x8 b = *(bf16x8*)&Ks[(nt*16 + l15)*QP + kc*32 + quad*8];
        sacc[nt] = __builtin_amdgcn_mfma_f32_16x16x32_bf16(a, b, sacc[nt], 0, 0, 0);
      }
    }

    bool mlow  = (role == 1) && (kb == qb - 8);   // valid: key >= qi
    bool mhigh = (role == 1) && (kb == qb);       // valid: key <= qi
    float alpha[4];
#pragma unroll
    for (int r = 0; r < 4; ++r){
      int qi_local = w*16 + quad*4 + r;
      float mx = -INFINITY;
#pragma unroll
      for (int nt = 0; nt < 4; ++nt){
        int key = nt*16 + l15;
        float sv = sacc[nt][r]*SCALE;
        bool valid = (!mlow || key >= qi_local) && (!mhigh || key <= qi_local);
        sv = valid ? sv : -INFINITY;
        sacc[nt][r] = sv;
        mx = fmaxf(mx, sv);
      }
      mx = fmaxf(mx, __shfl_xor(mx,1)); mx = fmaxf(mx, __shfl_xor(mx,2));
      mx = fmaxf(mx, __shfl_xor(mx,4)); mx = fmaxf(mx, __shfl_xor(mx,8));
      float mn = fmaxf(m1[r], mx);
      alpha[r] = __expf(m1[r] - mn);
      float s0 = 0.f;
#pragma unroll
      for (int nt = 0; nt < 4; ++nt){
        float pe = __expf(sacc[nt][r] - mn);   // masked -> 0
        sacc[nt][r] = pe;
        s0 += pe;
      }
      s0 += __shfl_xor(s0,1); s0 += __shfl_xor(s0,2);
      s0 += __shfl_xor(s0,4); s0 += __shfl_xor(s0,8);
      l1[r] = l1[r]*alpha[r] + s0;
      m1[r] = mn;
    }
    // P: C-layout -> LDS row-major; wave-private round trip
#pragma unroll
    for (int nt = 0; nt < 4; ++nt)
#pragma unroll
      for (int r = 0; r < 4; ++r)
        Ps[(w*16 + quad*4 + r)*VP + nt*16 + l15] = (short)f2b(sacc[nt][r]);
#pragma unroll
    for (int dt = 0; dt < 8; ++dt)
#pragma unroll
      for (int r = 0; r < 4; ++r) oacc[dt][r] *= alpha[r];
#pragma unroll
    for (int kc2 = 0; kc2 < 2; ++kc2){
      bf16x8 pa = *(bf16x8*)&Ps[(w*16 + l15)*VP + kc2*32 + quad*8];
#pragma unroll
      for (int dt = 0; dt < 8; ++dt){
        bf16x8 vb8 = *(bf16x8*)&VTs[(dt*16 + l15)*VP + kc2*32 + quad*8];
        oacc[dt] = __builtin_amdgcn_mfma_f32_16x16x32_bf16(pa, vb8, oacc[dt], 0, 0, 0);
      }
    }
  }

  // ---- epilogue: race-free plain stores ----
#pragma unroll
  for (int r = 0; r < 4; ++r){
    float s2 = gl[r] / l1[r];
    size_t ob = ((size_t)(bb*SEQ + qb*64 + w*16 + quad*4 + r)*QH + g*NH + h)*DIM + l15;
    if (role == 0){
      float* op = slcbuf + ob;              // unique writer; full coverage
#pragma unroll
      for (int dt = 0; dt < 8; ++dt) op[dt*16] = s2 * oacc[dt][r];
    } else {
      float* op = out + ob;                 // unique writer; cmp already done
#pragma unroll
      for (int dt = 0; dt < 8; ++dt) op[dt*16] += s2 * oacc[dt][r];
    }
  }
}

// ---------------- kernel 4: merge (out += slcbuf) ---------------------------
__global__ __launch_bounds__(256) void merge_k(const float* __restrict__ slcbuf,
                                               float* __restrict__ out){
  int i = blockIdx.x * 256 + threadIdx.x;   // over 4096*8*128/4 float4s
  float4 a = ((const float4*)slcbuf)[i];
  float4 b = ((float4*)out)[i];
  b.x += a.x; b.y += a.y; b.z += a.z; b.w += a.w;
  ((float4*)out)[i] = b;
}

extern "C" void kernel_launch(void* const* d_in, const int* in_sizes, int n_in,
                              void* d_out, int out_size, void* d_ws, size_t ws_size,
                              hipStream_t stream) {
  const float* q      = (const float*)d_in[0];
  const float* k      = (const float*)d_in[1];
  const float* v      = (const float*)d_in[2];
  const float* w_k    = (const float*)d_in[3];
  const float* b_k    = (const float*)d_in[4];
  const float* w_v    = (const float*)d_in[5];
  const float* b_v    = (const float*)d_in[6];
  const float* w_gate = (const float*)d_in[7];
  const float* b_gate = (const float*)d_in[8];
  float* out = (float*)d_out;

  float* ws     = (float*)d_ws;
  float* Kc     = ws;                        // 16384 f32
  float* Vc     = ws + 16384;                // 16384 f32
  float* pp     = ws + 32768;                // 512*32 f32
  float* slcbuf = ws + 49152;                // 4.19M f32 (16.8 MB)
  ushort_t* Kb  = (ushort_t*)(ws + 4243456); // 4*2048*128 bf16 (2 MB)
  ushort_t* VT  = Kb + 1048576;              // 4*128*2048 bf16 (2 MB)

  prep_k    <<<256, 256, 0, stream>>>(k, v, Kb, VT);
  compress_k<<<256, 256, 0, stream>>>(k, v, w_k, b_k, w_v, b_v, Kc, Vc);
  cmp_attn_k<<<NB*KV*NQB*NH, 256, 0, stream>>>(q, Kc, Vc, w_gate, b_gate, pp, out);
  attn_k    <<<1024, 256, 0, stream>>>(q, Kb, VT, pp, w_gate, b_gate, slcbuf, out);
  merge_k   <<<4096, 256, 0, stream>>>(slcbuf, out);
}